// Round 1
// baseline (1510.445 us; speedup 1.0000x reference)
//
#include <hip/hip_runtime.h>

// Problem constants
#define B_   4
#define V_   8
#define L_   256
#define C_   1024
#define H_   16
#define O_   4
#define DH_  64
#define BV_  32      // B*V
#define M_   8192    // B*V*L
#define NEG_ (-1e9f)

// ---------- bf16 helpers (manual, RNE) ----------
__device__ __forceinline__ float bflo(unsigned int w) { return __uint_as_float(w << 16); }
__device__ __forceinline__ float bfhi(unsigned int w) { return __uint_as_float(w & 0xffff0000u); }
__device__ __forceinline__ float bf2f(unsigned short u) { return __uint_as_float(((unsigned int)u) << 16); }
__device__ __forceinline__ unsigned int f2bfbits(float f) {
    unsigned int i = __float_as_uint(f);
    return (i + 0x7fffu + ((i >> 16) & 1u)) >> 16;
}
__device__ __forceinline__ unsigned int packbf(float a, float b) {
    return f2bfbits(a) | (f2bfbits(b) << 16);
}

// ---------- 1) routing: avg-pool over L, MLP, log_softmax + gumbel softmax ----------
__global__ __launch_bounds__(256) void routing_k(
    const float* __restrict__ v, const float* __restrict__ W1,
    const float* __restrict__ W2, const float* __restrict__ b2,
    const float* __restrict__ gum, const float* __restrict__ tau,
    float* __restrict__ alphas)
{
    __shared__ float pooled[C_];
    __shared__ float red[4][O_];
    const int bv = blockIdx.x;
    const int t  = threadIdx.x;
    const float* vb = v + (size_t)bv * (L_ * C_);

    float a0 = 0.f, a1 = 0.f, a2 = 0.f, a3 = 0.f;
    for (int l = 0; l < L_; ++l) {
        const float* r = vb + (size_t)l * C_;
        a0 += r[t]; a1 += r[t + 256]; a2 += r[t + 512]; a3 += r[t + 768];
    }
    const float inv = 1.0f / (float)L_;
    pooled[t] = a0 * inv; pooled[t + 256] = a1 * inv;
    pooled[t + 512] = a2 * inv; pooled[t + 768] = a3 * inv;
    __syncthreads();

    float h0 = 0.f, h1 = 0.f;
    for (int c = 0; c < C_; ++c) {
        const float p = pooled[c];
        h0 = fmaf(p, W1[c * 512 + t], h0);
        h1 = fmaf(p, W1[c * 512 + t + 256], h1);
    }
    h0 = fmaxf(h0, 0.f); h1 = fmaxf(h1, 0.f);

    float part[O_];
#pragma unroll
    for (int o = 0; o < O_; ++o)
        part[o] = h0 * W2[t * O_ + o] + h1 * W2[(t + 256) * O_ + o];
#pragma unroll
    for (int off = 32; off >= 1; off >>= 1) {
#pragma unroll
        for (int o = 0; o < O_; ++o) part[o] += __shfl_down(part[o], off, 64);
    }
    const int wid = t >> 6, lane = t & 63;
    if (lane == 0) {
#pragma unroll
        for (int o = 0; o < O_; ++o) red[wid][o] = part[o];
    }
    __syncthreads();
    if (t == 0) {
        float lg[O_];
#pragma unroll
        for (int o = 0; o < O_; ++o)
            lg[o] = red[0][o] + red[1][o] + red[2][o] + red[3][o] + b2[o];
        float mx = fmaxf(fmaxf(lg[0], lg[1]), fmaxf(lg[2], lg[3]));
        float s = 0.f;
#pragma unroll
        for (int o = 0; o < O_; ++o) s += expf(lg[o] - mx);
        const float lse = logf(s) + mx;
        const float it = 1.0f / tau[0];
        float y[O_];
#pragma unroll
        for (int o = 0; o < O_; ++o) y[o] = (lg[o] - lse + gum[bv * O_ + o]) * it;
        float my = fmaxf(fmaxf(y[0], y[1]), fmaxf(y[2], y[3]));
        float z = 0.f;
#pragma unroll
        for (int o = 0; o < O_; ++o) { y[o] = expf(y[o] - my); z += y[o]; }
        const float iz = 1.0f / z;
#pragma unroll
        for (int o = 0; o < O_; ++o) alphas[bv * O_ + o] = y[o] * iz;
    }
}

// ---------- 2) mask canonicalize+pack: bits per (bv,l), bit o = masked ----------
// Detects on-device whether the bool input was materialized as i32 / f32 / u8.
__global__ __launch_bounds__(1024) void maskpack_k(
    const void* __restrict__ src, unsigned char* __restrict__ dst)
{
    __shared__ int v_word;  // 1 if every sampled 32-bit word looks like i32/f32 bool
    const int t = threadIdx.x;
    if (t == 0) v_word = 1;
    __syncthreads();
    const unsigned int* s32 = (const unsigned int*)src;
    const unsigned int w = s32[t];  // first 4096 bytes — safe for all encodings
    if (w > 1u && w != 0x3F800000u) atomicAnd(&v_word, 0);
    __syncthreads();
    const bool word_mode = (v_word != 0);  // i32 (0/1) or f32 (0/1.0f): nonzero test identical
    const unsigned char* s8 = (const unsigned char*)src;
#pragma unroll
    for (int i = 0; i < 8; ++i) {
        const int idx = t * 8 + i;          // 0..8191 = bv*256 + l
        const int bv = idx >> 8, l = idx & 255;
        unsigned int bits = 0;
#pragma unroll
        for (int o = 0; o < O_; ++o) {
            const int mi = (o * BV_ + bv) * L_ + l;
            const unsigned int m = word_mode ? (s32[mi] != 0u) : (s8[mi] != 0);
            bits |= m << o;
        }
        dst[idx] = (unsigned char)bits;
    }
}

// ---------- 3) generic tiled GEMM:  Y = X[M,1024] @ W[1024,1024] + bias ----------
// ABF16: A is bf16 (final GEMM on atted); PROJSTORE: store head-major bf16 proj.
template <bool ABF16, bool PROJSTORE>
__global__ __launch_bounds__(256) void gemm_k(
    const void* __restrict__ A_, const float* __restrict__ W,
    const float* __restrict__ bias, void* __restrict__ out_)
{
    __shared__ float As[16][68];
    __shared__ float Bs[16][68];
    const int t  = threadIdx.x;
    const int n0 = blockIdx.x * 64;
    const int m0 = blockIdx.y * 64;
    const int tx = t & 15, ty = t >> 4;
    const int lam = t >> 2, lak = (t & 3) * 4;   // A load: row, k-offset
    const int lbj = t >> 4, lbn = (t & 15) * 4;  // B load: k-row, n-offset

    float acc[4][4] = {};
    for (int kt = 0; kt < C_; kt += 16) {
        float a0, a1, a2, a3;
        if (!ABF16) {
            const float4 a = *(const float4*)((const float*)A_ + (size_t)(m0 + lam) * C_ + kt + lak);
            a0 = a.x; a1 = a.y; a2 = a.z; a3 = a.w;
        } else {
            const ushort4 a = *(const ushort4*)((const unsigned short*)A_ + (size_t)(m0 + lam) * C_ + kt + lak);
            a0 = bf2f(a.x); a1 = bf2f(a.y); a2 = bf2f(a.z); a3 = bf2f(a.w);
        }
        const float4 b = *(const float4*)(W + (size_t)(kt + lbj) * C_ + n0 + lbn);
        __syncthreads();  // protect prior iteration's readers
        As[lak + 0][lam] = a0; As[lak + 1][lam] = a1;
        As[lak + 2][lam] = a2; As[lak + 3][lam] = a3;
        *(float4*)&Bs[lbj][lbn] = b;
        __syncthreads();
#pragma unroll
        for (int k = 0; k < 16; ++k) {
            const float4 a4 = *(const float4*)&As[k][ty * 4];
            const float4 b4 = *(const float4*)&Bs[k][tx * 4];
            const float av[4]  = {a4.x, a4.y, a4.z, a4.w};
            const float bv4[4] = {b4.x, b4.y, b4.z, b4.w};
#pragma unroll
            for (int i = 0; i < 4; ++i)
#pragma unroll
                for (int j = 0; j < 4; ++j)
                    acc[i][j] = fmaf(av[i], bv4[j], acc[i][j]);
        }
    }
    float bs[4];
#pragma unroll
    for (int j = 0; j < 4; ++j) bs[j] = bias[n0 + tx * 4 + j];

    if (PROJSTORE) {
        unsigned short* dst = (unsigned short*)out_;
        const int h = n0 >> 6;  // 64-wide n-tile => single head per block
#pragma unroll
        for (int i = 0; i < 4; ++i) {
            const int r = m0 + ty * 4 + i;
            const int bv = r >> 8, l = r & 255;
            const float o0 = acc[i][0] + bs[0], o1 = acc[i][1] + bs[1];
            const float o2 = acc[i][2] + bs[2], o3 = acc[i][3] + bs[3];
            uint2 val; val.x = packbf(o0, o1); val.y = packbf(o2, o3);
            *(uint2*)(dst + (((size_t)bv * H_ + h) * L_ + l) * DH_ + tx * 4) = val;
        }
    } else {
        float* dst = (float*)out_;
#pragma unroll
        for (int i = 0; i < 4; ++i) {
            const int r = m0 + ty * 4 + i;
            const float4 val = make_float4(acc[i][0] + bs[0], acc[i][1] + bs[1],
                                           acc[i][2] + bs[2], acc[i][3] + bs[3]);
            *(float4*)(dst + (size_t)r * C_ + n0 + tx * 4) = val;
        }
    }
}

// ---------- 4) attention: block = (b,v,h); thread = q-row; 2-pass online softmax ----------
__global__ __launch_bounds__(256) void attn_k(
    const unsigned short* __restrict__ qq, const unsigned short* __restrict__ kk,
    const unsigned short* __restrict__ vv, const unsigned char* __restrict__ mpk,
    const float* __restrict__ alphas, unsigned short* __restrict__ atted)
{
    __shared__ unsigned short kkL[L_][72];  // bf16, row stride 72 (16B aligned rows)
    __shared__ unsigned short vvL[L_][72];
    __shared__ unsigned char mk[L_];
    __shared__ float al[O_];
    const int h  = blockIdx.x;
    const int bv = blockIdx.y;
    const int t  = threadIdx.x;
    const size_t hb = ((size_t)bv * H_ + h) * (L_ * DH_);

    {   // stage K and V rows (row t, 64 bf16 each)
        const uint4* gk = (const uint4*)(kk + hb + (size_t)t * DH_);
        const uint4* gv = (const uint4*)(vv + hb + (size_t)t * DH_);
#pragma unroll
        for (int i = 0; i < 8; ++i) {
            const uint4 wk = gk[i], wv2 = gv[i];
            unsigned int* pk2 = (unsigned int*)&kkL[t][i * 8];
            unsigned int* pv2 = (unsigned int*)&vvL[t][i * 8];
            pk2[0] = wk.x; pk2[1] = wk.y; pk2[2] = wk.z; pk2[3] = wk.w;
            pv2[0] = wv2.x; pv2[1] = wv2.y; pv2[2] = wv2.z; pv2[3] = wv2.w;
        }
    }
    mk[t] = mpk[bv * L_ + t];
    if (t < O_) al[t] = alphas[bv * O_ + t];

    float q[DH_];
    {   // own q-row into registers
        const uint4* gq = (const uint4*)(qq + hb + (size_t)t * DH_);
#pragma unroll
        for (int i = 0; i < 8; ++i) {
            const uint4 w = gq[i];
            q[i * 8 + 0] = bflo(w.x); q[i * 8 + 1] = bfhi(w.x);
            q[i * 8 + 2] = bflo(w.y); q[i * 8 + 3] = bfhi(w.y);
            q[i * 8 + 4] = bflo(w.z); q[i * 8 + 5] = bfhi(w.z);
            q[i * 8 + 6] = bflo(w.w); q[i * 8 + 7] = bfhi(w.w);
        }
    }
    __syncthreads();

    // pass 1: per-order online max / Z over masked scores (exact NEG semantics)
    float m[O_], Z[O_];
#pragma unroll
    for (int o = 0; o < O_; ++o) { m[o] = -3.0e38f; Z[o] = 0.f; }
    for (int k = 0; k < L_; ++k) {
        const uint4* kr = (const uint4*)&kkL[k][0];
        float s = 0.f;
#pragma unroll
        for (int i = 0; i < 8; ++i) {
            const uint4 w = kr[i];
            s = fmaf(q[i * 8 + 0], bflo(w.x), s); s = fmaf(q[i * 8 + 1], bfhi(w.x), s);
            s = fmaf(q[i * 8 + 2], bflo(w.y), s); s = fmaf(q[i * 8 + 3], bfhi(w.y), s);
            s = fmaf(q[i * 8 + 4], bflo(w.z), s); s = fmaf(q[i * 8 + 5], bfhi(w.z), s);
            s = fmaf(q[i * 8 + 6], bflo(w.w), s); s = fmaf(q[i * 8 + 7], bfhi(w.w), s);
        }
        s *= 0.125f;  // 1/sqrt(Dh)
        const unsigned int pk = mk[k];
#pragma unroll
        for (int o = 0; o < O_; ++o) {
            const float se = ((pk >> o) & 1u) ? NEG_ : s;
            if (se > m[o]) { Z[o] = Z[o] * __expf(m[o] - se) + 1.0f; m[o] = se; }
            else           { Z[o] += __expf(se - m[o]); }
        }
    }
    float coef[O_];
#pragma unroll
    for (int o = 0; o < O_; ++o) coef[o] = al[o] / Z[o];

    // pass 2: recompute scores, combined weight, accumulate P @ V
    float acc[DH_];
#pragma unroll
    for (int d = 0; d < DH_; ++d) acc[d] = 0.f;
    for (int k = 0; k < L_; ++k) {
        const uint4* kr = (const uint4*)&kkL[k][0];
        float s = 0.f;
#pragma unroll
        for (int i = 0; i < 8; ++i) {
            const uint4 w = kr[i];
            s = fmaf(q[i * 8 + 0], bflo(w.x), s); s = fmaf(q[i * 8 + 1], bfhi(w.x), s);
            s = fmaf(q[i * 8 + 2], bflo(w.y), s); s = fmaf(q[i * 8 + 3], bfhi(w.y), s);
            s = fmaf(q[i * 8 + 4], bflo(w.z), s); s = fmaf(q[i * 8 + 5], bfhi(w.z), s);
            s = fmaf(q[i * 8 + 6], bflo(w.w), s); s = fmaf(q[i * 8 + 7], bfhi(w.w), s);
        }
        s *= 0.125f;
        const unsigned int pk = mk[k];
        float wgt = 0.f;
#pragma unroll
        for (int o = 0; o < O_; ++o) {
            const float se = ((pk >> o) & 1u) ? NEG_ : s;
            wgt = fmaf(coef[o], __expf(se - m[o]), wgt);
        }
        const uint4* vr = (const uint4*)&vvL[k][0];
#pragma unroll
        for (int i = 0; i < 8; ++i) {
            const uint4 w = vr[i];
            acc[i * 8 + 0] = fmaf(wgt, bflo(w.x), acc[i * 8 + 0]);
            acc[i * 8 + 1] = fmaf(wgt, bfhi(w.x), acc[i * 8 + 1]);
            acc[i * 8 + 2] = fmaf(wgt, bflo(w.y), acc[i * 8 + 2]);
            acc[i * 8 + 3] = fmaf(wgt, bfhi(w.y), acc[i * 8 + 3]);
            acc[i * 8 + 4] = fmaf(wgt, bflo(w.z), acc[i * 8 + 4]);
            acc[i * 8 + 5] = fmaf(wgt, bfhi(w.z), acc[i * 8 + 5]);
            acc[i * 8 + 6] = fmaf(wgt, bflo(w.w), acc[i * 8 + 6]);
            acc[i * 8 + 7] = fmaf(wgt, bfhi(w.w), acc[i * 8 + 7]);
        }
    }
    // store atted row in [B,V,L,C] bf16, c = h*64 + d
    unsigned short* dst = atted + ((size_t)bv * L_ + t) * C_ + h * DH_;
#pragma unroll
    for (int i = 0; i < 8; ++i) {
        uint4 o4;
        o4.x = packbf(acc[i * 8 + 0], acc[i * 8 + 1]);
        o4.y = packbf(acc[i * 8 + 2], acc[i * 8 + 3]);
        o4.z = packbf(acc[i * 8 + 4], acc[i * 8 + 5]);
        o4.w = packbf(acc[i * 8 + 6], acc[i * 8 + 7]);
        ((uint4*)dst)[i] = o4;
    }
}

// ---------- launch ----------
extern "C" void kernel_launch(void* const* d_in, const int* in_sizes, int n_in,
                              void* d_out, int out_size, void* d_ws, size_t ws_size,
                              hipStream_t stream)
{
    (void)in_sizes; (void)n_in; (void)out_size; (void)ws_size;
    const float* v   = (const float*)d_in[0];
    const float* k   = (const float*)d_in[1];
    const float* q   = (const float*)d_in[2];
    const void*  msk = d_in[3];
    const float* tau = (const float*)d_in[4];
    // d_in[5] = training (unused; gumbel path is unconditional in reference)
    const float* gum = (const float*)d_in[6];
    const float* Wv  = (const float*)d_in[7];
    const float* bvp = (const float*)d_in[8];
    const float* Wk  = (const float*)d_in[9];
    const float* bkp = (const float*)d_in[10];
    const float* Wq  = (const float*)d_in[11];
    const float* bqp = (const float*)d_in[12];
    const float* Wm  = (const float*)d_in[13];
    const float* bmp = (const float*)d_in[14];
    const float* W1  = (const float*)d_in[15];
    const float* W2  = (const float*)d_in[16];
    const float* b2  = (const float*)d_in[17];
    float* out = (float*)d_out;

    char* ws = (char*)d_ws;
    float* alphas       = (float*)ws;                       // 128 f32
    unsigned char* mpk  = (unsigned char*)(ws + 1024);      // 8192 B packed masks
    unsigned short* qqw = (unsigned short*)(ws + 65536);    // 16 MB bf16 each
    unsigned short* kkw = qqw + (size_t)M_ * C_;
    unsigned short* vvw = kkw + (size_t)M_ * C_;
    unsigned short* atw = vvw + (size_t)M_ * C_;            // ends ~64.1 MB

    hipLaunchKernelGGL(routing_k, dim3(BV_), dim3(256), 0, stream,
                       v, W1, W2, b2, gum, tau, alphas);
    hipLaunchKernelGGL(maskpack_k, dim3(1), dim3(1024), 0, stream, msk, mpk);
    hipLaunchKernelGGL((gemm_k<false, true>), dim3(16, 128), dim3(256), 0, stream,
                       (const void*)q, Wq, bqp, (void*)qqw);
    hipLaunchKernelGGL((gemm_k<false, true>), dim3(16, 128), dim3(256), 0, stream,
                       (const void*)k, Wk, bkp, (void*)kkw);
    hipLaunchKernelGGL((gemm_k<false, true>), dim3(16, 128), dim3(256), 0, stream,
                       (const void*)v, Wv, bvp, (void*)vvw);
    hipLaunchKernelGGL(attn_k, dim3(H_, BV_), dim3(256), 0, stream,
                       qqw, kkw, vvw, mpk, alphas, atw);
    hipLaunchKernelGGL((gemm_k<true, false>), dim3(16, 128), dim3(256), 0, stream,
                       (const void*)atw, Wm, bmp, (void*)out);
}

// Round 2
// 699.884 us; speedup vs baseline: 2.1581x; 2.1581x over previous
//
#include <hip/hip_runtime.h>

// Problem constants
#define B_   4
#define V_   8
#define L_   256
#define C_   1024
#define H_   16
#define O_   4
#define DH_  64
#define BV_  32      // B*V
#define M_   8192    // B*V*L
#define NEG_ (-1e9f)

typedef short bf16x8 __attribute__((ext_vector_type(8)));
typedef float f32x4 __attribute__((ext_vector_type(4)));

// ---------- bf16 helpers (manual, RNE) ----------
__device__ __forceinline__ float bflo(unsigned int w) { return __uint_as_float(w << 16); }
__device__ __forceinline__ float bfhi(unsigned int w) { return __uint_as_float(w & 0xffff0000u); }
__device__ __forceinline__ float bf2f(unsigned short u) { return __uint_as_float(((unsigned int)u) << 16); }
__device__ __forceinline__ unsigned int f2bfbits(float f) {
    unsigned int i = __float_as_uint(f);
    return (i + 0x7fffu + ((i >> 16) & 1u)) >> 16;
}
__device__ __forceinline__ unsigned int packbf(float a, float b) {
    return f2bfbits(a) | (f2bfbits(b) << 16);
}

// ---------- 1) routing: avg-pool over L, MLP, log_softmax + gumbel softmax ----------
__global__ __launch_bounds__(256) void routing_k(
    const float* __restrict__ v, const float* __restrict__ W1,
    const float* __restrict__ W2, const float* __restrict__ b2,
    const float* __restrict__ gum, const float* __restrict__ tau,
    float* __restrict__ alphas)
{
    __shared__ float pooled[C_];
    __shared__ float red[4][O_];
    const int bv = blockIdx.x;
    const int t  = threadIdx.x;
    const float* vb = v + (size_t)bv * (L_ * C_);

    float a0 = 0.f, a1 = 0.f, a2 = 0.f, a3 = 0.f;
    for (int l = 0; l < L_; ++l) {
        const float* r = vb + (size_t)l * C_;
        a0 += r[t]; a1 += r[t + 256]; a2 += r[t + 512]; a3 += r[t + 768];
    }
    const float inv = 1.0f / (float)L_;
    pooled[t] = a0 * inv; pooled[t + 256] = a1 * inv;
    pooled[t + 512] = a2 * inv; pooled[t + 768] = a3 * inv;
    __syncthreads();

    float h0 = 0.f, h1 = 0.f;
    for (int c = 0; c < C_; ++c) {
        const float p = pooled[c];
        h0 = fmaf(p, W1[c * 512 + t], h0);
        h1 = fmaf(p, W1[c * 512 + t + 256], h1);
    }
    h0 = fmaxf(h0, 0.f); h1 = fmaxf(h1, 0.f);

    float part[O_];
#pragma unroll
    for (int o = 0; o < O_; ++o)
        part[o] = h0 * W2[t * O_ + o] + h1 * W2[(t + 256) * O_ + o];
#pragma unroll
    for (int off = 32; off >= 1; off >>= 1) {
#pragma unroll
        for (int o = 0; o < O_; ++o) part[o] += __shfl_down(part[o], off, 64);
    }
    const int wid = t >> 6, lane = t & 63;
    if (lane == 0) {
#pragma unroll
        for (int o = 0; o < O_; ++o) red[wid][o] = part[o];
    }
    __syncthreads();
    if (t == 0) {
        float lg[O_];
#pragma unroll
        for (int o = 0; o < O_; ++o)
            lg[o] = red[0][o] + red[1][o] + red[2][o] + red[3][o] + b2[o];
        float mx = fmaxf(fmaxf(lg[0], lg[1]), fmaxf(lg[2], lg[3]));
        float s = 0.f;
#pragma unroll
        for (int o = 0; o < O_; ++o) s += expf(lg[o] - mx);
        const float lse = logf(s) + mx;
        const float it = 1.0f / tau[0];
        float y[O_];
#pragma unroll
        for (int o = 0; o < O_; ++o) y[o] = (lg[o] - lse + gum[bv * O_ + o]) * it;
        float my = fmaxf(fmaxf(y[0], y[1]), fmaxf(y[2], y[3]));
        float z = 0.f;
#pragma unroll
        for (int o = 0; o < O_; ++o) { y[o] = expf(y[o] - my); z += y[o]; }
        const float iz = 1.0f / z;
#pragma unroll
        for (int o = 0; o < O_; ++o) alphas[bv * O_ + o] = y[o] * iz;
    }
}

// ---------- 2) mask canonicalize+pack ----------
__global__ __launch_bounds__(1024) void maskpack_k(
    const void* __restrict__ src, unsigned char* __restrict__ dst)
{
    __shared__ int v_word;
    const int t = threadIdx.x;
    if (t == 0) v_word = 1;
    __syncthreads();
    const unsigned int* s32 = (const unsigned int*)src;
    const unsigned int w = s32[t];
    if (w > 1u && w != 0x3F800000u) atomicAnd(&v_word, 0);
    __syncthreads();
    const bool word_mode = (v_word != 0);
    const unsigned char* s8 = (const unsigned char*)src;
#pragma unroll
    for (int i = 0; i < 8; ++i) {
        const int idx = t * 8 + i;
        const int bv = idx >> 8, l = idx & 255;
        unsigned int bits = 0;
#pragma unroll
        for (int o = 0; o < O_; ++o) {
            const int mi = (o * BV_ + bv) * L_ + l;
            const unsigned int m = word_mode ? (s32[mi] != 0u) : (s8[mi] != 0);
            bits |= m << o;
        }
        dst[idx] = (unsigned char)bits;
    }
}

// ---------- 3) MFMA bf16 GEMM:  Y[M,1024] = X[M,1024] @ W[1024,1024] + bias ----------
// 128x128 tile, BK=32, 4 waves, 64x64 wave-tile of 4x4 16x16x32 fragments.
// ABF16: A is bf16 (final GEMM). PROJSTORE: store head-major bf16 projections.
template <bool ABF16, bool PROJSTORE>
__global__ __launch_bounds__(256) void mgemm_k(
    const void* __restrict__ A_, const float* __restrict__ W,
    const float* __restrict__ bias, void* __restrict__ out_)
{
    __shared__ unsigned short As[128][40];  // +8 bf16 pad: 80 B row stride (16B aligned)
    __shared__ unsigned short Bs[128][40];  // stored n-major: Bs[n][k]
    const int t = threadIdx.x;
    const int n0 = blockIdx.x * 128;
    const int m0 = blockIdx.y * 128;
    const int w = t >> 6, lane = t & 63;
    const int wm = (w >> 1) * 64, wn = (w & 1) * 64;
    const int fr = lane & 15;   // fragment row (A) / col (B,D)
    const int fq = lane >> 4;   // lane quad
    const int ak = fq * 8;      // k-offset within fragment (bf16 elems)

    const int arow = t >> 1, akh = (t & 1) * 16;  // A staging: row, k-half
    const int bn = t & 127, bkq = (t >> 7) * 16;  // B staging: n-col, k-half

    f32x4 acc[4][4] = {};

    for (int kt = 0; kt < C_; kt += 32) {
        // ---- global loads into regs ----
        uint4 aw0, aw1;
        if (!ABF16) {
            const float* ap = (const float*)A_ + (size_t)(m0 + arow) * C_ + kt + akh;
            const float4 f0 = *(const float4*)(ap + 0);
            const float4 f1 = *(const float4*)(ap + 4);
            const float4 f2 = *(const float4*)(ap + 8);
            const float4 f3 = *(const float4*)(ap + 12);
            aw0.x = packbf(f0.x, f0.y); aw0.y = packbf(f0.z, f0.w);
            aw0.z = packbf(f1.x, f1.y); aw0.w = packbf(f1.z, f1.w);
            aw1.x = packbf(f2.x, f2.y); aw1.y = packbf(f2.z, f2.w);
            aw1.z = packbf(f3.x, f3.y); aw1.w = packbf(f3.z, f3.w);
        } else {
            const unsigned short* ap = (const unsigned short*)A_ + (size_t)(m0 + arow) * C_ + kt + akh;
            aw0 = ((const uint4*)ap)[0];
            aw1 = ((const uint4*)ap)[1];
        }
        float bfv[16];
        {
            const float* wp = W + (size_t)(kt + bkq) * C_ + n0 + bn;
#pragma unroll
            for (int j = 0; j < 16; ++j) bfv[j] = wp[(size_t)j * C_];
        }
        uint4 bw0, bw1;
        bw0.x = packbf(bfv[0], bfv[1]);  bw0.y = packbf(bfv[2], bfv[3]);
        bw0.z = packbf(bfv[4], bfv[5]);  bw0.w = packbf(bfv[6], bfv[7]);
        bw1.x = packbf(bfv[8], bfv[9]);  bw1.y = packbf(bfv[10], bfv[11]);
        bw1.z = packbf(bfv[12], bfv[13]); bw1.w = packbf(bfv[14], bfv[15]);

        __syncthreads();  // prior iteration's readers done
        *(uint4*)&As[arow][akh]     = aw0;
        *(uint4*)&As[arow][akh + 8] = aw1;
        *(uint4*)&Bs[bn][bkq]       = bw0;
        *(uint4*)&Bs[bn][bkq + 8]   = bw1;
        __syncthreads();

        bf16x8 af[4], bfr[4];
#pragma unroll
        for (int i = 0; i < 4; ++i)
            af[i] = *(const bf16x8*)&As[wm + i * 16 + fr][ak];
#pragma unroll
        for (int j = 0; j < 4; ++j)
            bfr[j] = *(const bf16x8*)&Bs[wn + j * 16 + fr][ak];
#pragma unroll
        for (int i = 0; i < 4; ++i)
#pragma unroll
            for (int j = 0; j < 4; ++j)
                acc[i][j] = __builtin_amdgcn_mfma_f32_16x16x32_bf16(af[i], bfr[j], acc[i][j], 0, 0, 0);
    }

    // ---- epilogue: D[row][col], col=lane&15, row=(lane>>4)*4+r (m89-verified) ----
#pragma unroll
    for (int j = 0; j < 4; ++j) {
        const int gcol = n0 + wn + j * 16 + fr;
        const float bj = bias[gcol];
#pragma unroll
        for (int i = 0; i < 4; ++i) {
#pragma unroll
            for (int r = 0; r < 4; ++r) {
                const int grow = m0 + wm + i * 16 + fq * 4 + r;
                const float val = acc[i][j][r] + bj;
                if (PROJSTORE) {
                    const int bv = grow >> 8, l = grow & 255;
                    const int h = gcol >> 6, dh = gcol & 63;
                    ((unsigned short*)out_)[(((size_t)bv * H_ + h) * L_ + l) * DH_ + dh] =
                        (unsigned short)f2bfbits(val);
                } else {
                    ((float*)out_)[(size_t)grow * C_ + gcol] = val;
                }
            }
        }
    }
}

// ---------- 4) attention: block = (b,v,h); thread = q-row; 2-pass online softmax ----------
__global__ __launch_bounds__(256) void attn_k(
    const unsigned short* __restrict__ qq, const unsigned short* __restrict__ kk,
    const unsigned short* __restrict__ vv, const unsigned char* __restrict__ mpk,
    const float* __restrict__ alphas, unsigned short* __restrict__ atted)
{
    __shared__ unsigned short kkL[L_][72];
    __shared__ unsigned short vvL[L_][72];
    __shared__ unsigned char mk[L_];
    __shared__ float al[O_];
    const int h  = blockIdx.x;
    const int bv = blockIdx.y;
    const int t  = threadIdx.x;
    const size_t hb = ((size_t)bv * H_ + h) * (L_ * DH_);

    {
        const uint4* gk = (const uint4*)(kk + hb + (size_t)t * DH_);
        const uint4* gv = (const uint4*)(vv + hb + (size_t)t * DH_);
#pragma unroll
        for (int i = 0; i < 8; ++i) {
            const uint4 wk = gk[i], wv2 = gv[i];
            unsigned int* pk2 = (unsigned int*)&kkL[t][i * 8];
            unsigned int* pv2 = (unsigned int*)&vvL[t][i * 8];
            pk2[0] = wk.x; pk2[1] = wk.y; pk2[2] = wk.z; pk2[3] = wk.w;
            pv2[0] = wv2.x; pv2[1] = wv2.y; pv2[2] = wv2.z; pv2[3] = wv2.w;
        }
    }
    mk[t] = mpk[bv * L_ + t];
    if (t < O_) al[t] = alphas[bv * O_ + t];

    float q[DH_];
    {
        const uint4* gq = (const uint4*)(qq + hb + (size_t)t * DH_);
#pragma unroll
        for (int i = 0; i < 8; ++i) {
            const uint4 w = gq[i];
            q[i * 8 + 0] = bflo(w.x); q[i * 8 + 1] = bfhi(w.x);
            q[i * 8 + 2] = bflo(w.y); q[i * 8 + 3] = bfhi(w.y);
            q[i * 8 + 4] = bflo(w.z); q[i * 8 + 5] = bfhi(w.z);
            q[i * 8 + 6] = bflo(w.w); q[i * 8 + 7] = bfhi(w.w);
        }
    }
    __syncthreads();

    float m[O_], Z[O_];
#pragma unroll
    for (int o = 0; o < O_; ++o) { m[o] = -3.0e38f; Z[o] = 0.f; }
    for (int k = 0; k < L_; ++k) {
        const uint4* kr = (const uint4*)&kkL[k][0];
        float s = 0.f;
#pragma unroll
        for (int i = 0; i < 8; ++i) {
            const uint4 w = kr[i];
            s = fmaf(q[i * 8 + 0], bflo(w.x), s); s = fmaf(q[i * 8 + 1], bfhi(w.x), s);
            s = fmaf(q[i * 8 + 2], bflo(w.y), s); s = fmaf(q[i * 8 + 3], bfhi(w.y), s);
            s = fmaf(q[i * 8 + 4], bflo(w.z), s); s = fmaf(q[i * 8 + 5], bfhi(w.z), s);
            s = fmaf(q[i * 8 + 6], bflo(w.w), s); s = fmaf(q[i * 8 + 7], bfhi(w.w), s);
        }
        s *= 0.125f;
        const unsigned int pk = mk[k];
#pragma unroll
        for (int o = 0; o < O_; ++o) {
            const float se = ((pk >> o) & 1u) ? NEG_ : s;
            if (se > m[o]) { Z[o] = Z[o] * __expf(m[o] - se) + 1.0f; m[o] = se; }
            else           { Z[o] += __expf(se - m[o]); }
        }
    }
    float coef[O_];
#pragma unroll
    for (int o = 0; o < O_; ++o) coef[o] = al[o] / Z[o];

    float acc[DH_];
#pragma unroll
    for (int d = 0; d < DH_; ++d) acc[d] = 0.f;
    for (int k = 0; k < L_; ++k) {
        const uint4* kr = (const uint4*)&kkL[k][0];
        float s = 0.f;
#pragma unroll
        for (int i = 0; i < 8; ++i) {
            const uint4 w = kr[i];
            s = fmaf(q[i * 8 + 0], bflo(w.x), s); s = fmaf(q[i * 8 + 1], bfhi(w.x), s);
            s = fmaf(q[i * 8 + 2], bflo(w.y), s); s = fmaf(q[i * 8 + 3], bfhi(w.y), s);
            s = fmaf(q[i * 8 + 4], bflo(w.z), s); s = fmaf(q[i * 8 + 5], bfhi(w.z), s);
            s = fmaf(q[i * 8 + 6], bflo(w.w), s); s = fmaf(q[i * 8 + 7], bfhi(w.w), s);
        }
        s *= 0.125f;
        const unsigned int pk = mk[k];
        float wgt = 0.f;
#pragma unroll
        for (int o = 0; o < O_; ++o) {
            const float se = ((pk >> o) & 1u) ? NEG_ : s;
            wgt = fmaf(coef[o], __expf(se - m[o]), wgt);
        }
        const uint4* vr = (const uint4*)&vvL[k][0];
#pragma unroll
        for (int i = 0; i < 8; ++i) {
            const uint4 w = vr[i];
            acc[i * 8 + 0] = fmaf(wgt, bflo(w.x), acc[i * 8 + 0]);
            acc[i * 8 + 1] = fmaf(wgt, bfhi(w.x), acc[i * 8 + 1]);
            acc[i * 8 + 2] = fmaf(wgt, bflo(w.y), acc[i * 8 + 2]);
            acc[i * 8 + 3] = fmaf(wgt, bfhi(w.y), acc[i * 8 + 3]);
            acc[i * 8 + 4] = fmaf(wgt, bflo(w.z), acc[i * 8 + 4]);
            acc[i * 8 + 5] = fmaf(wgt, bfhi(w.z), acc[i * 8 + 5]);
            acc[i * 8 + 6] = fmaf(wgt, bflo(w.w), acc[i * 8 + 6]);
            acc[i * 8 + 7] = fmaf(wgt, bfhi(w.w), acc[i * 8 + 7]);
        }
    }
    unsigned short* dst = atted + ((size_t)bv * L_ + t) * C_ + h * DH_;
#pragma unroll
    for (int i = 0; i < 8; ++i) {
        uint4 o4;
        o4.x = packbf(acc[i * 8 + 0], acc[i * 8 + 1]);
        o4.y = packbf(acc[i * 8 + 2], acc[i * 8 + 3]);
        o4.z = packbf(acc[i * 8 + 4], acc[i * 8 + 5]);
        o4.w = packbf(acc[i * 8 + 6], acc[i * 8 + 7]);
        ((uint4*)dst)[i] = o4;
    }
}

// ---------- launch ----------
extern "C" void kernel_launch(void* const* d_in, const int* in_sizes, int n_in,
                              void* d_out, int out_size, void* d_ws, size_t ws_size,
                              hipStream_t stream)
{
    (void)in_sizes; (void)n_in; (void)out_size; (void)ws_size;
    const float* v   = (const float*)d_in[0];
    const float* k   = (const float*)d_in[1];
    const float* q   = (const float*)d_in[2];
    const void*  msk = d_in[3];
    const float* tau = (const float*)d_in[4];
    const float* gum = (const float*)d_in[6];
    const float* Wv  = (const float*)d_in[7];
    const float* bvp = (const float*)d_in[8];
    const float* Wk  = (const float*)d_in[9];
    const float* bkp = (const float*)d_in[10];
    const float* Wq  = (const float*)d_in[11];
    const float* bqp = (const float*)d_in[12];
    const float* Wm  = (const float*)d_in[13];
    const float* bmp = (const float*)d_in[14];
    const float* W1  = (const float*)d_in[15];
    const float* W2  = (const float*)d_in[16];
    const float* b2  = (const float*)d_in[17];
    float* out = (float*)d_out;

    char* ws = (char*)d_ws;
    float* alphas       = (float*)ws;                       // 128 f32
    unsigned char* mpk  = (unsigned char*)(ws + 1024);      // 8192 B packed masks
    unsigned short* qqw = (unsigned short*)(ws + 65536);    // 16 MB bf16 each
    unsigned short* kkw = qqw + (size_t)M_ * C_;
    unsigned short* vvw = kkw + (size_t)M_ * C_;
    unsigned short* atw = vvw + (size_t)M_ * C_;            // ends ~64.1 MB

    hipLaunchKernelGGL(routing_k, dim3(BV_), dim3(256), 0, stream,
                       v, W1, W2, b2, gum, tau, alphas);
    hipLaunchKernelGGL(maskpack_k, dim3(1), dim3(1024), 0, stream, msk, mpk);
    hipLaunchKernelGGL((mgemm_k<false, true>), dim3(8, 64), dim3(256), 0, stream,
                       (const void*)q, Wq, bqp, (void*)qqw);
    hipLaunchKernelGGL((mgemm_k<false, true>), dim3(8, 64), dim3(256), 0, stream,
                       (const void*)k, Wk, bkp, (void*)kkw);
    hipLaunchKernelGGL((mgemm_k<false, true>), dim3(8, 64), dim3(256), 0, stream,
                       (const void*)v, Wv, bvp, (void*)vvw);
    hipLaunchKernelGGL(attn_k, dim3(H_, BV_), dim3(256), 0, stream,
                       qqw, kkw, vvw, mpk, alphas, atw);
    hipLaunchKernelGGL((mgemm_k<true, false>), dim3(8, 64), dim3(256), 0, stream,
                       (const void*)atw, Wm, bmp, (void*)out);
}

// Round 3
// 405.288 us; speedup vs baseline: 3.7268x; 1.7269x over previous
//
#include <hip/hip_runtime.h>

// Problem constants
#define B_   4
#define V_   8
#define L_   256
#define C_   1024
#define H_   16
#define O_   4
#define DH_  64
#define BV_  32      // B*V
#define M_   8192    // B*V*L
#define NEG_ (-1e9f)

typedef short bf16x8 __attribute__((ext_vector_type(8)));
typedef float f32x4 __attribute__((ext_vector_type(4)));

// ---------- bf16 helpers (manual, RNE) ----------
__device__ __forceinline__ float bflo(unsigned int w) { return __uint_as_float(w << 16); }
__device__ __forceinline__ float bfhi(unsigned int w) { return __uint_as_float(w & 0xffff0000u); }
__device__ __forceinline__ float bf2f(unsigned short u) { return __uint_as_float(((unsigned int)u) << 16); }
__device__ __forceinline__ unsigned int f2bfbits(float f) {
    unsigned int i = __float_as_uint(f);
    return (i + 0x7fffu + ((i >> 16) & 1u)) >> 16;
}
__device__ __forceinline__ unsigned int packbf(float a, float b) {
    return f2bfbits(a) | (f2bfbits(b) << 16);
}

// ---------- 1) routing ----------
__global__ __launch_bounds__(256) void routing_k(
    const float* __restrict__ v, const float* __restrict__ W1,
    const float* __restrict__ W2, const float* __restrict__ b2,
    const float* __restrict__ gum, const float* __restrict__ tau,
    float* __restrict__ alphas)
{
    __shared__ float pooled[C_];
    __shared__ float red[4][O_];
    const int bv = blockIdx.x;
    const int t  = threadIdx.x;
    const float* vb = v + (size_t)bv * (L_ * C_);

    float a0 = 0.f, a1 = 0.f, a2 = 0.f, a3 = 0.f;
    for (int l = 0; l < L_; ++l) {
        const float* r = vb + (size_t)l * C_;
        a0 += r[t]; a1 += r[t + 256]; a2 += r[t + 512]; a3 += r[t + 768];
    }
    const float inv = 1.0f / (float)L_;
    pooled[t] = a0 * inv; pooled[t + 256] = a1 * inv;
    pooled[t + 512] = a2 * inv; pooled[t + 768] = a3 * inv;
    __syncthreads();

    float h0 = 0.f, h1 = 0.f;
    for (int c = 0; c < C_; ++c) {
        const float p = pooled[c];
        h0 = fmaf(p, W1[c * 512 + t], h0);
        h1 = fmaf(p, W1[c * 512 + t + 256], h1);
    }
    h0 = fmaxf(h0, 0.f); h1 = fmaxf(h1, 0.f);

    float part[O_];
#pragma unroll
    for (int o = 0; o < O_; ++o)
        part[o] = h0 * W2[t * O_ + o] + h1 * W2[(t + 256) * O_ + o];
#pragma unroll
    for (int off = 32; off >= 1; off >>= 1) {
#pragma unroll
        for (int o = 0; o < O_; ++o) part[o] += __shfl_down(part[o], off, 64);
    }
    const int wid = t >> 6, lane = t & 63;
    if (lane == 0) {
#pragma unroll
        for (int o = 0; o < O_; ++o) red[wid][o] = part[o];
    }
    __syncthreads();
    if (t == 0) {
        float lg[O_];
#pragma unroll
        for (int o = 0; o < O_; ++o)
            lg[o] = red[0][o] + red[1][o] + red[2][o] + red[3][o] + b2[o];
        float mx = fmaxf(fmaxf(lg[0], lg[1]), fmaxf(lg[2], lg[3]));
        float s = 0.f;
#pragma unroll
        for (int o = 0; o < O_; ++o) s += expf(lg[o] - mx);
        const float lse = logf(s) + mx;
        const float it = 1.0f / tau[0];
        float y[O_];
#pragma unroll
        for (int o = 0; o < O_; ++o) y[o] = (lg[o] - lse + gum[bv * O_ + o]) * it;
        float my = fmaxf(fmaxf(y[0], y[1]), fmaxf(y[2], y[3]));
        float z = 0.f;
#pragma unroll
        for (int o = 0; o < O_; ++o) { y[o] = expf(y[o] - my); z += y[o]; }
        const float iz = 1.0f / z;
#pragma unroll
        for (int o = 0; o < O_; ++o) alphas[bv * O_ + o] = y[o] * iz;
    }
}

// ---------- 2) mask canonicalize+pack ----------
__global__ __launch_bounds__(1024) void maskpack_k(
    const void* __restrict__ src, unsigned char* __restrict__ dst)
{
    __shared__ int v_word;
    const int t = threadIdx.x;
    if (t == 0) v_word = 1;
    __syncthreads();
    const unsigned int* s32 = (const unsigned int*)src;
    const unsigned int w = s32[t];
    if (w > 1u && w != 0x3F800000u) atomicAnd(&v_word, 0);
    __syncthreads();
    const bool word_mode = (v_word != 0);
    const unsigned char* s8 = (const unsigned char*)src;
#pragma unroll
    for (int i = 0; i < 8; ++i) {
        const int idx = t * 8 + i;
        const int bv = idx >> 8, l = idx & 255;
        unsigned int bits = 0;
#pragma unroll
        for (int o = 0; o < O_; ++o) {
            const int mi = (o * BV_ + bv) * L_ + l;
            const unsigned int m = word_mode ? (s32[mi] != 0u) : (s8[mi] != 0);
            bits |= m << o;
        }
        dst[idx] = (unsigned char)bits;
    }
}

// ---------- 3) MFMA bf16 GEMM (unchanged from round 2) ----------
template <bool ABF16, bool PROJSTORE>
__global__ __launch_bounds__(256) void mgemm_k(
    const void* __restrict__ A_, const float* __restrict__ W,
    const float* __restrict__ bias, void* __restrict__ out_)
{
    __shared__ unsigned short As[128][40];
    __shared__ unsigned short Bs[128][40];
    const int t = threadIdx.x;
    const int n0 = blockIdx.x * 128;
    const int m0 = blockIdx.y * 128;
    const int w = t >> 6, lane = t & 63;
    const int wm = (w >> 1) * 64, wn = (w & 1) * 64;
    const int fr = lane & 15;
    const int fq = lane >> 4;
    const int ak = fq * 8;

    const int arow = t >> 1, akh = (t & 1) * 16;
    const int bn = t & 127, bkq = (t >> 7) * 16;

    f32x4 acc[4][4] = {};

    for (int kt = 0; kt < C_; kt += 32) {
        uint4 aw0, aw1;
        if (!ABF16) {
            const float* ap = (const float*)A_ + (size_t)(m0 + arow) * C_ + kt + akh;
            const float4 f0 = *(const float4*)(ap + 0);
            const float4 f1 = *(const float4*)(ap + 4);
            const float4 f2 = *(const float4*)(ap + 8);
            const float4 f3 = *(const float4*)(ap + 12);
            aw0.x = packbf(f0.x, f0.y); aw0.y = packbf(f0.z, f0.w);
            aw0.z = packbf(f1.x, f1.y); aw0.w = packbf(f1.z, f1.w);
            aw1.x = packbf(f2.x, f2.y); aw1.y = packbf(f2.z, f2.w);
            aw1.z = packbf(f3.x, f3.y); aw1.w = packbf(f3.z, f3.w);
        } else {
            const unsigned short* ap = (const unsigned short*)A_ + (size_t)(m0 + arow) * C_ + kt + akh;
            aw0 = ((const uint4*)ap)[0];
            aw1 = ((const uint4*)ap)[1];
        }
        float bfv[16];
        {
            const float* wp = W + (size_t)(kt + bkq) * C_ + n0 + bn;
#pragma unroll
            for (int j = 0; j < 16; ++j) bfv[j] = wp[(size_t)j * C_];
        }
        uint4 bw0, bw1;
        bw0.x = packbf(bfv[0], bfv[1]);  bw0.y = packbf(bfv[2], bfv[3]);
        bw0.z = packbf(bfv[4], bfv[5]);  bw0.w = packbf(bfv[6], bfv[7]);
        bw1.x = packbf(bfv[8], bfv[9]);  bw1.y = packbf(bfv[10], bfv[11]);
        bw1.z = packbf(bfv[12], bfv[13]); bw1.w = packbf(bfv[14], bfv[15]);

        __syncthreads();
        *(uint4*)&As[arow][akh]     = aw0;
        *(uint4*)&As[arow][akh + 8] = aw1;
        *(uint4*)&Bs[bn][bkq]       = bw0;
        *(uint4*)&Bs[bn][bkq + 8]   = bw1;
        __syncthreads();

        bf16x8 af[4], bfr[4];
#pragma unroll
        for (int i = 0; i < 4; ++i)
            af[i] = *(const bf16x8*)&As[wm + i * 16 + fr][ak];
#pragma unroll
        for (int j = 0; j < 4; ++j)
            bfr[j] = *(const bf16x8*)&Bs[wn + j * 16 + fr][ak];
#pragma unroll
        for (int i = 0; i < 4; ++i)
#pragma unroll
            for (int j = 0; j < 4; ++j)
                acc[i][j] = __builtin_amdgcn_mfma_f32_16x16x32_bf16(af[i], bfr[j], acc[i][j], 0, 0, 0);
    }

#pragma unroll
    for (int j = 0; j < 4; ++j) {
        const int gcol = n0 + wn + j * 16 + fr;
        const float bj = bias[gcol];
#pragma unroll
        for (int i = 0; i < 4; ++i) {
#pragma unroll
            for (int r = 0; r < 4; ++r) {
                const int grow = m0 + wm + i * 16 + fq * 4 + r;
                const float val = acc[i][j][r] + bj;
                if (PROJSTORE) {
                    const int bvb = grow >> 8, l = grow & 255;
                    const int hh = gcol >> 6, dh = gcol & 63;
                    ((unsigned short*)out_)[(((size_t)bvb * H_ + hh) * L_ + l) * DH_ + dh] =
                        (unsigned short)f2bfbits(val);
                } else {
                    ((float*)out_)[(size_t)grow * C_ + gcol] = val;
                }
            }
        }
    }
}

// ---------- 4) MFMA attention: block=(h,bv), 4 waves x 64 q-rows ----------
// S = QK^T/8 via mfma; att_map[q,k] = t * sum_o unmask_o(k)*alpha_o/T_o[q],
// t = exp(s/8) (no stabilizer: |s/8| << 80), T_o = sum over unmasked t.
// Exactly matches reference softmax because masked exp(-1e9 - m) == 0 in fp32.
__global__ __launch_bounds__(256) void attn_mfma_k(
    const unsigned short* __restrict__ qq, const unsigned short* __restrict__ kk,
    const unsigned short* __restrict__ vv, const unsigned char* __restrict__ mpk,
    const float* __restrict__ alphas, unsigned short* __restrict__ atted)
{
    __shared__ unsigned short Ksh[L_][70];          // word stride 35 (odd*… -> 2-way max)
    __shared__ unsigned short Vt[DH_][262];         // V transposed, word stride 131
    __shared__ unsigned short Pt[4][16][34];        // per-wave P tile, word stride 17
    __shared__ __align__(16) unsigned char mkT[16][16];
    __shared__ float al[O_];

    const int h = blockIdx.x, bv = blockIdx.y;
    const int t = threadIdx.x;
    const int w = t >> 6, lane = t & 63;
    const int fr = lane & 15, fq = lane >> 4;
    const int q0 = w * 64;
    const size_t hb = ((size_t)bv * H_ + h) * (L_ * DH_);

    // ---- staging ----
    {   // K row t -> Ksh[t][:]
        const uint4* gk = (const uint4*)(kk + hb + (size_t)t * DH_);
#pragma unroll
        for (int i = 0; i < 8; ++i) *(uint4*)&Ksh[t][i * 8] = gk[i];
    }
    {   // V row t -> Vt[:][t] (transpose)
        const uint4* gv = (const uint4*)(vv + hb + (size_t)t * DH_);
#pragma unroll
        for (int i = 0; i < 8; ++i) {
            const uint4 wv = gv[i];
            const unsigned int ws4[4] = {wv.x, wv.y, wv.z, wv.w};
#pragma unroll
            for (int jd = 0; jd < 4; ++jd) {
                Vt[i * 8 + jd * 2 + 0][t] = (unsigned short)(ws4[jd] & 0xffffu);
                Vt[i * 8 + jd * 2 + 1][t] = (unsigned short)(ws4[jd] >> 16);
            }
        }
    }
    mkT[t & 15][t >> 4] = mpk[bv * L_ + t];
    if (t < O_) al[t] = alphas[bv * O_ + t];

    // Q fragments for this wave's 64 rows (global, head-major layout)
    bf16x8 aq[4][2];
#pragma unroll
    for (int i = 0; i < 4; ++i)
#pragma unroll
        for (int kkh = 0; kkh < 2; ++kkh)
            aq[i][kkh] = *(const bf16x8*)(qq + hb + (size_t)(q0 + i * 16 + fr) * DH_ + kkh * 32 + fq * 8);

    __syncthreads();

    float alr[4] = {al[0], al[1], al[2], al[3]};
    // mask nibbles for this lane's columns {j*16+fr : j=0..15}
    const uint4 nv = *(const uint4*)&mkT[fr][0];
    const unsigned int nb[4] = {nv.x, nv.y, nv.z, nv.w};

    for (int i = 0; i < 4; ++i) {  // q subgroups of 16 rows
        // ---- pass A: T_o[q] ----
        float T[4][4] = {};  // [o][r]
#pragma unroll
        for (int j = 0; j < 16; ++j) {
            const bf16x8 kb0 = *(const bf16x8*)&Ksh[j * 16 + fr][fq * 8];
            const bf16x8 kb1 = *(const bf16x8*)&Ksh[j * 16 + fr][32 + fq * 8];
            f32x4 s = {0.f, 0.f, 0.f, 0.f};
            s = __builtin_amdgcn_mfma_f32_16x16x32_bf16(aq[i][0], kb0, s, 0, 0, 0);
            s = __builtin_amdgcn_mfma_f32_16x16x32_bf16(aq[i][1], kb1, s, 0, 0, 0);
            const unsigned int nib = (nb[j >> 2] >> ((j & 3) * 8)) & 0xFu;
            const unsigned int ivb = nib ^ 0xFu;
            const float b0f = (float)(ivb & 1u);
            const float b1f = (float)((ivb >> 1) & 1u);
            const float b2f = (float)((ivb >> 2) & 1u);
            const float b3f = (float)((ivb >> 3) & 1u);
#pragma unroll
            for (int r = 0; r < 4; ++r) {
                const float tt = __expf(s[r] * 0.125f);
                T[0][r] = fmaf(tt, b0f, T[0][r]);
                T[1][r] = fmaf(tt, b1f, T[1][r]);
                T[2][r] = fmaf(tt, b2f, T[2][r]);
                T[3][r] = fmaf(tt, b3f, T[3][r]);
            }
        }
        // reduce over the 16 fr-lanes; then c_o[r] = alpha_o / T_o
        float c[4][4];
#pragma unroll
        for (int o = 0; o < 4; ++o)
#pragma unroll
            for (int r = 0; r < 4; ++r) {
                float x = T[o][r];
                x += __shfl_xor(x, 1, 64);
                x += __shfl_xor(x, 2, 64);
                x += __shfl_xor(x, 4, 64);
                x += __shfl_xor(x, 8, 64);
                c[o][r] = alr[o] * __builtin_amdgcn_rcpf(fmaxf(x, 1e-30f));
            }

        // ---- pass B: recompute S, w = t*cfac, P@V via mfma ----
        f32x4 pacc[4] = {};
#pragma unroll
        for (int kb = 0; kb < 8; ++kb) {
            bf16x8 vb[4];
#pragma unroll
            for (int n = 0; n < 4; ++n)
                vb[n] = *(const bf16x8*)&Vt[n * 16 + fr][kb * 32 + fq * 8];
#pragma unroll
            for (int jj = 0; jj < 2; ++jj) {
                const int j = kb * 2 + jj;
                const bf16x8 kb0 = *(const bf16x8*)&Ksh[j * 16 + fr][fq * 8];
                const bf16x8 kb1 = *(const bf16x8*)&Ksh[j * 16 + fr][32 + fq * 8];
                f32x4 s = {0.f, 0.f, 0.f, 0.f};
                s = __builtin_amdgcn_mfma_f32_16x16x32_bf16(aq[i][0], kb0, s, 0, 0, 0);
                s = __builtin_amdgcn_mfma_f32_16x16x32_bf16(aq[i][1], kb1, s, 0, 0, 0);
                const unsigned int nib = (nb[j >> 2] >> ((j & 3) * 8)) & 0xFu;
                const unsigned int ivb = nib ^ 0xFu;
                const float b0f = (float)(ivb & 1u);
                const float b1f = (float)((ivb >> 1) & 1u);
                const float b2f = (float)((ivb >> 2) & 1u);
                const float b3f = (float)((ivb >> 3) & 1u);
#pragma unroll
                for (int r = 0; r < 4; ++r) {
                    const float tt = __expf(s[r] * 0.125f);
                    float cf = b0f * c[0][r];
                    cf = fmaf(b1f, c[1][r], cf);
                    cf = fmaf(b2f, c[2][r], cf);
                    cf = fmaf(b3f, c[3][r], cf);
                    const float wv = tt * cf;
                    Pt[w][fq * 4 + r][jj * 16 + fr] = (unsigned short)f2bfbits(wv);
                }
            }
            asm volatile("s_waitcnt lgkmcnt(0)" ::: "memory");  // Pt cross-lane RAW
            const bf16x8 pa = *(const bf16x8*)&Pt[w][fr][fq * 8];
#pragma unroll
            for (int n = 0; n < 4; ++n)
                pacc[n] = __builtin_amdgcn_mfma_f32_16x16x32_bf16(pa, vb[n], pacc[n], 0, 0, 0);
        }
        // ---- epilogue for subgroup i: atted[bv][row][h*64+d] ----
#pragma unroll
        for (int n = 0; n < 4; ++n) {
#pragma unroll
            for (int r = 0; r < 4; ++r) {
                const int row = q0 + i * 16 + fq * 4 + r;
                const int d = n * 16 + fr;
                atted[((size_t)bv * L_ + row) * C_ + h * DH_ + d] =
                    (unsigned short)f2bfbits(pacc[n][r]);
            }
        }
    }
}

// ---------- launch ----------
extern "C" void kernel_launch(void* const* d_in, const int* in_sizes, int n_in,
                              void* d_out, int out_size, void* d_ws, size_t ws_size,
                              hipStream_t stream)
{
    (void)in_sizes; (void)n_in; (void)out_size; (void)ws_size;
    const float* v   = (const float*)d_in[0];
    const float* k   = (const float*)d_in[1];
    const float* q   = (const float*)d_in[2];
    const void*  msk = d_in[3];
    const float* tau = (const float*)d_in[4];
    const float* gum = (const float*)d_in[6];
    const float* Wv  = (const float*)d_in[7];
    const float* bvp = (const float*)d_in[8];
    const float* Wk  = (const float*)d_in[9];
    const float* bkp = (const float*)d_in[10];
    const float* Wq  = (const float*)d_in[11];
    const float* bqp = (const float*)d_in[12];
    const float* Wm  = (const float*)d_in[13];
    const float* bmp = (const float*)d_in[14];
    const float* W1  = (const float*)d_in[15];
    const float* W2  = (const float*)d_in[16];
    const float* b2  = (const float*)d_in[17];
    float* out = (float*)d_out;

    char* ws = (char*)d_ws;
    float* alphas       = (float*)ws;                       // 128 f32
    unsigned char* mpk  = (unsigned char*)(ws + 1024);      // 8192 B packed masks
    unsigned short* qqw = (unsigned short*)(ws + 65536);    // 16 MB bf16 each
    unsigned short* kkw = qqw + (size_t)M_ * C_;
    unsigned short* vvw = kkw + (size_t)M_ * C_;
    unsigned short* atw = vvw + (size_t)M_ * C_;            // ends ~64.1 MB

    hipLaunchKernelGGL(routing_k, dim3(BV_), dim3(256), 0, stream,
                       v, W1, W2, b2, gum, tau, alphas);
    hipLaunchKernelGGL(maskpack_k, dim3(1), dim3(1024), 0, stream, msk, mpk);
    hipLaunchKernelGGL((mgemm_k<false, true>), dim3(8, 64), dim3(256), 0, stream,
                       (const void*)q, Wq, bqp, (void*)qqw);
    hipLaunchKernelGGL((mgemm_k<false, true>), dim3(8, 64), dim3(256), 0, stream,
                       (const void*)k, Wk, bkp, (void*)kkw);
    hipLaunchKernelGGL((mgemm_k<false, true>), dim3(8, 64), dim3(256), 0, stream,
                       (const void*)v, Wv, bvp, (void*)vvw);
    hipLaunchKernelGGL(attn_mfma_k, dim3(H_, BV_), dim3(256), 0, stream,
                       qqw, kkw, vvw, mpk, alphas, atw);
    hipLaunchKernelGGL((mgemm_k<true, false>), dim3(8, 64), dim3(256), 0, stream,
                       (const void*)atw, Wm, bmp, (void*)out);
}

// Round 4
// 374.376 us; speedup vs baseline: 4.0346x; 1.0826x over previous
//
#include <hip/hip_runtime.h>

// Problem constants
#define B_   4
#define V_   8
#define L_   256
#define C_   1024
#define H_   16
#define O_   4
#define DH_  64
#define BV_  32      // B*V
#define M_   8192    // B*V*L
#define NEG_ (-1e9f)

typedef short bf16x8 __attribute__((ext_vector_type(8)));
typedef float f32x4 __attribute__((ext_vector_type(4)));

// ---------- bf16 helpers (manual, RNE) ----------
__device__ __forceinline__ float bflo(unsigned int w) { return __uint_as_float(w << 16); }
__device__ __forceinline__ float bfhi(unsigned int w) { return __uint_as_float(w & 0xffff0000u); }
__device__ __forceinline__ float bf2f(unsigned short u) { return __uint_as_float(((unsigned int)u) << 16); }
__device__ __forceinline__ unsigned int f2bfbits(float f) {
    unsigned int i = __float_as_uint(f);
    return (i + 0x7fffu + ((i >> 16) & 1u)) >> 16;
}
__device__ __forceinline__ unsigned int packbf(float a, float b) {
    return f2bfbits(a) | (f2bfbits(b) << 16);
}

// ---------- 1) routing ----------
__global__ __launch_bounds__(256) void routing_k(
    const float* __restrict__ v, const float* __restrict__ W1,
    const float* __restrict__ W2, const float* __restrict__ b2,
    const float* __restrict__ gum, const float* __restrict__ tau,
    float* __restrict__ alphas)
{
    __shared__ float pooled[C_];
    __shared__ float red[4][O_];
    const int bv = blockIdx.x;
    const int t  = threadIdx.x;
    const float* vb = v + (size_t)bv * (L_ * C_);

    float a0 = 0.f, a1 = 0.f, a2 = 0.f, a3 = 0.f;
    for (int l = 0; l < L_; ++l) {
        const float* r = vb + (size_t)l * C_;
        a0 += r[t]; a1 += r[t + 256]; a2 += r[t + 512]; a3 += r[t + 768];
    }
    const float inv = 1.0f / (float)L_;
    pooled[t] = a0 * inv; pooled[t + 256] = a1 * inv;
    pooled[t + 512] = a2 * inv; pooled[t + 768] = a3 * inv;
    __syncthreads();

    float h0 = 0.f, h1 = 0.f;
    for (int c = 0; c < C_; ++c) {
        const float p = pooled[c];
        h0 = fmaf(p, W1[c * 512 + t], h0);
        h1 = fmaf(p, W1[c * 512 + t + 256], h1);
    }
    h0 = fmaxf(h0, 0.f); h1 = fmaxf(h1, 0.f);

    float part[O_];
#pragma unroll
    for (int o = 0; o < O_; ++o)
        part[o] = h0 * W2[t * O_ + o] + h1 * W2[(t + 256) * O_ + o];
#pragma unroll
    for (int off = 32; off >= 1; off >>= 1) {
#pragma unroll
        for (int o = 0; o < O_; ++o) part[o] += __shfl_down(part[o], off, 64);
    }
    const int wid = t >> 6, lane = t & 63;
    if (lane == 0) {
#pragma unroll
        for (int o = 0; o < O_; ++o) red[wid][o] = part[o];
    }
    __syncthreads();
    if (t == 0) {
        float lg[O_];
#pragma unroll
        for (int o = 0; o < O_; ++o)
            lg[o] = red[0][o] + red[1][o] + red[2][o] + red[3][o] + b2[o];
        float mx = fmaxf(fmaxf(lg[0], lg[1]), fmaxf(lg[2], lg[3]));
        float s = 0.f;
#pragma unroll
        for (int o = 0; o < O_; ++o) s += expf(lg[o] - mx);
        const float lse = logf(s) + mx;
        const float it = 1.0f / tau[0];
        float y[O_];
#pragma unroll
        for (int o = 0; o < O_; ++o) y[o] = (lg[o] - lse + gum[bv * O_ + o]) * it;
        float my = fmaxf(fmaxf(y[0], y[1]), fmaxf(y[2], y[3]));
        float z = 0.f;
#pragma unroll
        for (int o = 0; o < O_; ++o) { y[o] = expf(y[o] - my); z += y[o]; }
        const float iz = 1.0f / z;
#pragma unroll
        for (int o = 0; o < O_; ++o) alphas[bv * O_ + o] = y[o] * iz;
    }
}

// ---------- 2) mask canonicalize+pack ----------
__global__ __launch_bounds__(1024) void maskpack_k(
    const void* __restrict__ src, unsigned char* __restrict__ dst)
{
    __shared__ int v_word;
    const int t = threadIdx.x;
    if (t == 0) v_word = 1;
    __syncthreads();
    const unsigned int* s32 = (const unsigned int*)src;
    const unsigned int w = s32[t];
    if (w > 1u && w != 0x3F800000u) atomicAnd(&v_word, 0);
    __syncthreads();
    const bool word_mode = (v_word != 0);
    const unsigned char* s8 = (const unsigned char*)src;
#pragma unroll
    for (int i = 0; i < 8; ++i) {
        const int idx = t * 8 + i;
        const int bv = idx >> 8, l = idx & 255;
        unsigned int bits = 0;
#pragma unroll
        for (int o = 0; o < O_; ++o) {
            const int mi = (o * BV_ + bv) * L_ + l;
            const unsigned int m = word_mode ? (s32[mi] != 0u) : (s8[mi] != 0);
            bits |= m << o;
        }
        dst[idx] = (unsigned char)bits;
    }
}

// ---------- 2b) weight prep: Wt[n][k] = bf16(W[k][n]) ----------
__global__ __launch_bounds__(256) void wprep_k(
    const float* __restrict__ W, unsigned short* __restrict__ Wt)
{
    __shared__ float tile[64][65];
    const int t = threadIdx.x;
    const int k0 = blockIdx.x * 64, n0 = blockIdx.y * 64;
    const int r = t >> 2, c4 = (t & 3) * 16;
#pragma unroll
    for (int i = 0; i < 4; ++i) {
        const float4 f = *(const float4*)(W + (size_t)(k0 + r) * C_ + n0 + c4 + i * 4);
        tile[r][c4 + i * 4 + 0] = f.x; tile[r][c4 + i * 4 + 1] = f.y;
        tile[r][c4 + i * 4 + 2] = f.z; tile[r][c4 + i * 4 + 3] = f.w;
    }
    __syncthreads();
    unsigned int ow[8];
#pragma unroll
    for (int p = 0; p < 8; ++p)
        ow[p] = packbf(tile[c4 + 2 * p][r], tile[c4 + 2 * p + 1][r]);
    unsigned short* dst = Wt + (size_t)(n0 + r) * C_ + k0 + c4;
    uint4 o0; o0.x = ow[0]; o0.y = ow[1]; o0.z = ow[2]; o0.w = ow[3];
    uint4 o1; o1.x = ow[4]; o1.y = ow[5]; o1.z = ow[6]; o1.w = ow[7];
    *(uint4*)dst = o0;
    *(uint4*)(dst + 8) = o1;
}

// ---------- 3) MFMA bf16 GEMM, B from pre-transposed bf16 Wt[n][k] ----------
template <bool ABF16, bool PROJSTORE>
__global__ __launch_bounds__(256) void mgemm_k(
    const void* __restrict__ A_, const unsigned short* __restrict__ Wt,
    const float* __restrict__ bias, void* __restrict__ out_)
{
    __shared__ unsigned short As[128][40];
    __shared__ unsigned short Bs[128][40];
    const int t = threadIdx.x;
    const int n0 = blockIdx.x * 128;
    const int m0 = blockIdx.y * 128;
    const int w = t >> 6, lane = t & 63;
    const int wm = (w >> 1) * 64, wn = (w & 1) * 64;
    const int fr = lane & 15;
    const int fq = lane >> 4;
    const int ak = fq * 8;

    const int arow = t >> 1, akh = (t & 1) * 16;

    f32x4 acc[4][4] = {};

    for (int kt = 0; kt < C_; kt += 32) {
        uint4 aw0, aw1;
        if (!ABF16) {
            const float* ap = (const float*)A_ + (size_t)(m0 + arow) * C_ + kt + akh;
            const float4 f0 = *(const float4*)(ap + 0);
            const float4 f1 = *(const float4*)(ap + 4);
            const float4 f2 = *(const float4*)(ap + 8);
            const float4 f3 = *(const float4*)(ap + 12);
            aw0.x = packbf(f0.x, f0.y); aw0.y = packbf(f0.z, f0.w);
            aw0.z = packbf(f1.x, f1.y); aw0.w = packbf(f1.z, f1.w);
            aw1.x = packbf(f2.x, f2.y); aw1.y = packbf(f2.z, f2.w);
            aw1.z = packbf(f3.x, f3.y); aw1.w = packbf(f3.z, f3.w);
        } else {
            const unsigned short* ap = (const unsigned short*)A_ + (size_t)(m0 + arow) * C_ + kt + akh;
            aw0 = ((const uint4*)ap)[0];
            aw1 = ((const uint4*)ap)[1];
        }
        const unsigned short* bp = Wt + (size_t)(n0 + arow) * C_ + kt + akh;
        const uint4 bw0 = *(const uint4*)bp;
        const uint4 bw1 = *(const uint4*)(bp + 8);

        __syncthreads();
        *(uint4*)&As[arow][akh]     = aw0;
        *(uint4*)&As[arow][akh + 8] = aw1;
        *(uint4*)&Bs[arow][akh]     = bw0;
        *(uint4*)&Bs[arow][akh + 8] = bw1;
        __syncthreads();

        bf16x8 af[4], bfr[4];
#pragma unroll
        for (int i = 0; i < 4; ++i)
            af[i] = *(const bf16x8*)&As[wm + i * 16 + fr][ak];
#pragma unroll
        for (int j = 0; j < 4; ++j)
            bfr[j] = *(const bf16x8*)&Bs[wn + j * 16 + fr][ak];
#pragma unroll
        for (int i = 0; i < 4; ++i)
#pragma unroll
            for (int j = 0; j < 4; ++j)
                acc[i][j] = __builtin_amdgcn_mfma_f32_16x16x32_bf16(af[i], bfr[j], acc[i][j], 0, 0, 0);
    }

#pragma unroll
    for (int j = 0; j < 4; ++j) {
        const int gcol = n0 + wn + j * 16 + fr;
        const float bj = bias[gcol];
#pragma unroll
        for (int i = 0; i < 4; ++i) {
#pragma unroll
            for (int r = 0; r < 4; ++r) {
                const int grow = m0 + wm + i * 16 + fq * 4 + r;
                const float val = acc[i][j][r] + bj;
                if (PROJSTORE) {
                    const int bvb = grow >> 8, l = grow & 255;
                    const int hh = gcol >> 6, dh = gcol & 63;
                    ((unsigned short*)out_)[(((size_t)bvb * H_ + hh) * L_ + l) * DH_ + dh] =
                        (unsigned short)f2bfbits(val);
                } else {
                    ((float*)out_)[(size_t)grow * C_ + gcol] = val;
                }
            }
        }
    }
}

// ---------- 4) MFMA attention v2: single QK pass, reg-held exp, packed Pt ----------
// k-interleave within each 32-k block: mem col c' <-> k via
//   sigma(k) = (k&15)*2 + (k>>4)   (store),  pi = sigma^{-1} (read)
// Both the P tile and V tile use it => MFMA k-permutation cancels.
__global__ __launch_bounds__(256) void attn_mfma_k(
    const unsigned short* __restrict__ qq, const unsigned short* __restrict__ kk,
    const unsigned short* __restrict__ vv, const unsigned char* __restrict__ mpk,
    const float* __restrict__ alphas, unsigned short* __restrict__ atted)
{
    __shared__ unsigned short Ksh[L_][70];    // 35-dword rows
    __shared__ unsigned short Vt[DH_][262];   // V^T, sigma-permuted cols, 131-dword rows
    __shared__ unsigned short Pt[4][16][40];  // per-wave P tile, 20-dword rows (2-way writes)
    __shared__ __align__(16) unsigned char mkT[16][16];
    __shared__ float al[O_];

    const int h = blockIdx.x, bv = blockIdx.y;
    const int t = threadIdx.x;
    const int w = t >> 6, lane = t & 63;
    const int fr = lane & 15, fq = lane >> 4;
    const int q0 = w * 64;
    const size_t hb = ((size_t)bv * H_ + h) * (L_ * DH_);

    // ---- staging ----
    {   // K row t -> Ksh[t][:]
        const uint4* gk = (const uint4*)(kk + hb + (size_t)t * DH_);
#pragma unroll
        for (int i = 0; i < 8; ++i) *(uint4*)&Ksh[t][i * 8] = gk[i];
    }
    {   // V row t -> Vt[:][sigma-col]
        const int tc = (t & 0xE0) | ((t & 15) << 1) | ((t >> 4) & 1);
        const uint4* gv = (const uint4*)(vv + hb + (size_t)t * DH_);
#pragma unroll
        for (int i = 0; i < 8; ++i) {
            const uint4 wv = gv[i];
            const unsigned int ws4[4] = {wv.x, wv.y, wv.z, wv.w};
#pragma unroll
            for (int jd = 0; jd < 4; ++jd) {
                Vt[i * 8 + jd * 2 + 0][tc] = (unsigned short)(ws4[jd] & 0xffffu);
                Vt[i * 8 + jd * 2 + 1][tc] = (unsigned short)(ws4[jd] >> 16);
            }
        }
    }
    mkT[t & 15][t >> 4] = mpk[bv * L_ + t];
    if (t < O_) al[t] = alphas[bv * O_ + t];

    // Q fragments for this wave's 64 rows
    bf16x8 aq[4][2];
#pragma unroll
    for (int i = 0; i < 4; ++i)
#pragma unroll
        for (int kh = 0; kh < 2; ++kh)
            aq[i][kh] = *(const bf16x8*)(qq + hb + (size_t)(q0 + i * 16 + fr) * DH_ + kh * 32 + fq * 8);

    __syncthreads();

    const float alr0 = al[0], alr1 = al[1], alr2 = al[2], alr3 = al[3];
    // mask bytes for this lane's columns {j*16+fr : j=0..15}
    const uint4 nv = *(const uint4*)&mkT[fr][0];
    const unsigned int nb[4] = {nv.x, nv.y, nv.z, nv.w};

    for (int i = 0; i < 4; ++i) {  // q subgroups of 16 rows
        // ---- single QK pass: s -> ts (kept in regs), accumulate T_o ----
        f32x4 ts[16];
        float T[4][4] = {};  // [o][r]
#pragma unroll
        for (int j = 0; j < 16; ++j) {
            const bf16x8 kb0 = *(const bf16x8*)&Ksh[j * 16 + fr][fq * 8];
            const bf16x8 kb1 = *(const bf16x8*)&Ksh[j * 16 + fr][32 + fq * 8];
            f32x4 s = {0.f, 0.f, 0.f, 0.f};
            s = __builtin_amdgcn_mfma_f32_16x16x32_bf16(aq[i][0], kb0, s, 0, 0, 0);
            s = __builtin_amdgcn_mfma_f32_16x16x32_bf16(aq[i][1], kb1, s, 0, 0, 0);
            const unsigned int ivb = ((nb[j >> 2] >> ((j & 3) * 8)) & 0xFu) ^ 0xFu;
            const float b0f = (float)(ivb & 1u);
            const float b1f = (float)((ivb >> 1) & 1u);
            const float b2f = (float)((ivb >> 2) & 1u);
            const float b3f = (float)((ivb >> 3) & 1u);
            f32x4 e;
#pragma unroll
            for (int r = 0; r < 4; ++r) {
                e[r] = __expf(s[r] * 0.125f);
                T[0][r] = fmaf(e[r], b0f, T[0][r]);
                T[1][r] = fmaf(e[r], b1f, T[1][r]);
                T[2][r] = fmaf(e[r], b2f, T[2][r]);
                T[3][r] = fmaf(e[r], b3f, T[3][r]);
            }
            ts[j] = e;
        }
        // reduce T over the 16 fr-lanes; c_o[r] = alpha_o / T_o
        float c[4][4];
#pragma unroll
        for (int o = 0; o < 4; ++o) {
            const float alo = (o == 0) ? alr0 : (o == 1) ? alr1 : (o == 2) ? alr2 : alr3;
#pragma unroll
            for (int r = 0; r < 4; ++r) {
                float x = T[o][r];
                x += __shfl_xor(x, 1, 64);
                x += __shfl_xor(x, 2, 64);
                x += __shfl_xor(x, 4, 64);
                x += __shfl_xor(x, 8, 64);
                c[o][r] = alo * __builtin_amdgcn_rcpf(fmaxf(x, 1e-30f));
            }
        }

        // ---- PV: pack P (dword, k-interleaved), exchange via Pt, MFMA with V ----
        f32x4 pacc[4] = {};
#pragma unroll
        for (int kb = 0; kb < 8; ++kb) {
            bf16x8 vb[4];
#pragma unroll
            for (int n = 0; n < 4; ++n)
                vb[n] = *(const bf16x8*)&Vt[n * 16 + fr][kb * 32 + fq * 8];

            const int j0 = kb * 2, j1 = j0 + 1;
            const unsigned int iv0 = ((nb[j0 >> 2] >> ((j0 & 3) * 8)) & 0xFu) ^ 0xFu;
            const unsigned int iv1 = ((nb[j1 >> 2] >> ((j1 & 3) * 8)) & 0xFu) ^ 0xFu;
            const float a00 = (float)(iv0 & 1u), a01 = (float)((iv0 >> 1) & 1u);
            const float a02 = (float)((iv0 >> 2) & 1u), a03 = (float)((iv0 >> 3) & 1u);
            const float a10 = (float)(iv1 & 1u), a11 = (float)((iv1 >> 1) & 1u);
            const float a12 = (float)((iv1 >> 2) & 1u), a13 = (float)((iv1 >> 3) & 1u);
#pragma unroll
            for (int r = 0; r < 4; ++r) {
                float cf0 = a00 * c[0][r];
                cf0 = fmaf(a01, c[1][r], cf0);
                cf0 = fmaf(a02, c[2][r], cf0);
                cf0 = fmaf(a03, c[3][r], cf0);
                float cf1 = a10 * c[0][r];
                cf1 = fmaf(a11, c[1][r], cf1);
                cf1 = fmaf(a12, c[2][r], cf1);
                cf1 = fmaf(a13, c[3][r], cf1);
                // cols (fr, fr+16) of row fq*4+r -> one dword at dword-offset fr
                *(unsigned int*)&Pt[w][fq * 4 + r][fr * 2] =
                    packbf(ts[j0][r] * cf0, ts[j1][r] * cf1);
            }
            asm volatile("s_waitcnt lgkmcnt(0)" ::: "memory");  // cross-lane Pt RAW
            const bf16x8 pa = *(const bf16x8*)&Pt[w][fr][fq * 8];
#pragma unroll
            for (int n = 0; n < 4; ++n)
                pacc[n] = __builtin_amdgcn_mfma_f32_16x16x32_bf16(pa, vb[n], pacc[n], 0, 0, 0);
        }
        // ---- epilogue: atted[bv][row][h*64+d] ----
#pragma unroll
        for (int n = 0; n < 4; ++n) {
#pragma unroll
            for (int r = 0; r < 4; ++r) {
                const int row = q0 + i * 16 + fq * 4 + r;
                const int d = n * 16 + fr;
                atted[((size_t)bv * L_ + row) * C_ + h * DH_ + d] =
                    (unsigned short)f2bfbits(pacc[n][r]);
            }
        }
    }
}

// ---------- launch ----------
extern "C" void kernel_launch(void* const* d_in, const int* in_sizes, int n_in,
                              void* d_out, int out_size, void* d_ws, size_t ws_size,
                              hipStream_t stream)
{
    (void)in_sizes; (void)n_in; (void)out_size; (void)ws_size;
    const float* v   = (const float*)d_in[0];
    const float* k   = (const float*)d_in[1];
    const float* q   = (const float*)d_in[2];
    const void*  msk = d_in[3];
    const float* tau = (const float*)d_in[4];
    const float* gum = (const float*)d_in[6];
    const float* Wv  = (const float*)d_in[7];
    const float* bvp = (const float*)d_in[8];
    const float* Wk  = (const float*)d_in[9];
    const float* bkp = (const float*)d_in[10];
    const float* Wq  = (const float*)d_in[11];
    const float* bqp = (const float*)d_in[12];
    const float* Wm  = (const float*)d_in[13];
    const float* bmp = (const float*)d_in[14];
    const float* W1  = (const float*)d_in[15];
    const float* W2  = (const float*)d_in[16];
    const float* b2  = (const float*)d_in[17];
    float* out = (float*)d_out;

    char* ws = (char*)d_ws;
    float* alphas       = (float*)ws;                        // 128 f32
    unsigned char* mpk  = (unsigned char*)(ws + 1024);       // 8 KB packed masks
    unsigned short* Wt  = (unsigned short*)(ws + 65536);     // 2 MB bf16 W^T (reused 4x)
    unsigned short* qqw = (unsigned short*)(ws + 65536 + (size_t)2 * 1024 * 1024);
    unsigned short* kkw = qqw + (size_t)M_ * C_;             // 16 MB each
    unsigned short* vvw = kkw + (size_t)M_ * C_;
    unsigned short* atw = vvw + (size_t)M_ * C_;             // ends ~66.2 MB

    hipLaunchKernelGGL(routing_k, dim3(BV_), dim3(256), 0, stream,
                       v, W1, W2, b2, gum, tau, alphas);
    hipLaunchKernelGGL(maskpack_k, dim3(1), dim3(1024), 0, stream, msk, mpk);

    hipLaunchKernelGGL(wprep_k, dim3(16, 16), dim3(256), 0, stream, Wq, Wt);
    hipLaunchKernelGGL((mgemm_k<false, true>), dim3(8, 64), dim3(256), 0, stream,
                       (const void*)q, Wt, bqp, (void*)qqw);
    hipLaunchKernelGGL(wprep_k, dim3(16, 16), dim3(256), 0, stream, Wk, Wt);
    hipLaunchKernelGGL((mgemm_k<false, true>), dim3(8, 64), dim3(256), 0, stream,
                       (const void*)k, Wt, bkp, (void*)kkw);
    hipLaunchKernelGGL(wprep_k, dim3(16, 16), dim3(256), 0, stream, Wv, Wt);
    hipLaunchKernelGGL((mgemm_k<false, true>), dim3(8, 64), dim3(256), 0, stream,
                       (const void*)v, Wt, bvp, (void*)vvw);

    hipLaunchKernelGGL(attn_mfma_k, dim3(H_, BV_), dim3(256), 0, stream,
                       qqw, kkw, vvw, mpk, alphas, atw);

    hipLaunchKernelGGL(wprep_k, dim3(16, 16), dim3(256), 0, stream, Wm, Wt);
    hipLaunchKernelGGL((mgemm_k<true, false>), dim3(8, 64), dim3(256), 0, stream,
                       (const void*)atw, Wt, bmp, (void*)out);
}